// Round 5
// baseline (708.893 us; speedup 1.0000x reference)
//
#include <hip/hip_runtime.h>

typedef __bf16 bf16_t;
typedef __bf16 bf16x8_t __attribute__((ext_vector_type(8)));
typedef __bf16 bf16x4_t __attribute__((ext_vector_type(4)));
typedef float f32x4_t __attribute__((ext_vector_type(4)));
typedef unsigned short u16;
typedef unsigned int u32;

#define B_ 2
#define S_ 4096
#define NH_ 16
#define NKV_ 4
#define D_ 128
// attention runs in the exp2 domain: scale*log2e folded into Q at rope time
#define QSCALE_ 0.12751743f          // D^-0.5 * log2(e)
#define NEG2_ (-1442695040.0f)       // -1e9 * log2(e)

// async global->LDS, 16B per lane; LDS dest must be wave-uniform base (+lane*16 implicit)
__device__ __forceinline__ void load16(const bf16_t* g, bf16_t* l) {
  __builtin_amdgcn_global_load_lds(
      (__attribute__((address_space(1))) void*)(g),
      (__attribute__((address_space(3))) void*)(l),
      16, 0, 0);
}

// ---------------- fused fp32 -> bf16 convert (all 5 tensors, one launch) ----------------
__global__ __launch_bounds__(256) void cvt_all_kernel(const float* __restrict__ hs,
                                                      const float* __restrict__ Wq,
                                                      const float* __restrict__ Wk,
                                                      const float* __restrict__ Wv,
                                                      const float* __restrict__ Wo,
                                                      bf16_t* __restrict__ Xb,
                                                      bf16_t* __restrict__ Wb,
                                                      bf16_t* __restrict__ Wob) {
  int i = blockIdx.x * 256 + threadIdx.x;  // float4 index; ranges are 256-aligned (uniform branch)
  const float* src; bf16_t* dst; int local;
  if (i < 4194304)      { src = hs; dst = Xb;            local = i; }
  else if (i < 5242880) { src = Wq; dst = Wb;            local = i - 4194304; }
  else if (i < 5505024) { src = Wk; dst = Wb + 4194304;  local = i - 5242880; }
  else if (i < 5767168) { src = Wv; dst = Wb + 5242880;  local = i - 5505024; }
  else                  { src = Wo; dst = Wob;           local = i - 5767168; }
  float4 v = ((const float4*)src)[local];
  bf16x4_t o;
  o.x = (bf16_t)v.x; o.y = (bf16_t)v.y; o.z = (bf16_t)v.z; o.w = (bf16_t)v.w;
  *(bf16x4_t*)(dst + (size_t)local * 4) = o;
}

#define DRAIN2() asm volatile("s_waitcnt vmcnt(2)" ::: "memory")
#define DRAIN4() asm volatile("s_waitcnt vmcnt(4)" ::: "memory")
#define BARF() { __builtin_amdgcn_s_barrier(); asm volatile("" ::: "memory"); }

// ---------------- QKV GEMM: 256x128 tiles, 4-phase, 1 barrier/phase ----------------
#define QLDA_(BUF) { \
  _Pragma("unroll") for (int mi = 0; mi < 4; mi++) { \
    _Pragma("unroll") for (int ks = 0; ks < 2; ks++) { \
      a[mi][ks] = *(const bf16x8_t*)&As[BUF][ks][wr4 * 64 + mi * 16 + l15][(l4 ^ xr) * 8]; } } }

#define QLDB_(BUF, NP) { \
  _Pragma("unroll") for (int n2 = 0; n2 < 2; n2++) { \
    _Pragma("unroll") for (int ks = 0; ks < 2; ks++) { \
      b[(NP) * 2 + n2][ks] = *(const bf16x8_t*)&Bs[BUF][ks][wc2 * 64 + ((NP) * 2 + n2) * 16 + l15][(l4 ^ xr) * 8]; } } }

#define QMFMA_(NP) { \
  __builtin_amdgcn_s_setprio(1); \
  _Pragma("unroll") for (int mi = 0; mi < 4; mi++) { \
    _Pragma("unroll") for (int n2 = 0; n2 < 2; n2++) { \
      _Pragma("unroll") for (int ks = 0; ks < 2; ks++) { \
        acc[mi][(NP) * 2 + n2] = __builtin_amdgcn_mfma_f32_16x16x32_bf16( \
            a[mi][ks], b[(NP) * 2 + n2][ks], acc[mi][(NP) * 2 + n2], 0, 0, 0); } } } \
  __builtin_amdgcn_s_setprio(0); }

__global__ __launch_bounds__(512, 2) void gemm_qkv_kernel(const bf16_t* __restrict__ A,
                                                          const bf16_t* __restrict__ Bm,
                                                          bf16_t* __restrict__ Cb,
                                                          int M, int N, int K) {
  __shared__ __align__(16) bf16_t As[2][2][256][32];  // 64 KiB
  __shared__ __align__(16) bf16_t Bs[2][2][128][32];  // 32 KiB
  const int t = threadIdx.x;
  const int lane = t & 63;
  const int w = t >> 6;            // 0..7
  const int wr4 = w >> 1;          // 0..3 : M quarter (64 rows)
  const int wc2 = w & 1;           // 0..1 : N half (64 cols)
  const int l15 = lane & 15, l4 = lane >> 4;
  const int xr = (l15 >> 1) & 3;   // fragment-read granule XOR term
  const int sp = w >> 2;
  const int swi = w & 3;
  const int srow = lane >> 2;
  const int sg = lane & 3;
  const int scg = (srow >> 1) & 3;

  const int m0 = blockIdx.x * 256;
  const int n0 = blockIdx.y * 128;
  const bf16_t* Ablk = A + (size_t)m0 * K;
  const bf16_t* Bblk = Bm + (size_t)n0 * K;

  f32x4_t acc[4][4] = {};
  bf16x8_t a[4][2], b[4][2];

  const int nkt = K >> 6;
  const int nit = nkt >> 1;

  auto stageA = [&](int buf, int mp, int kt) {
#pragma unroll
    for (int c = 0; c < 2; c++) {
      int r0 = c * 128 + mp * 64;
      load16(Ablk + (size_t)(r0 + swi * 16 + srow) * K + kt * 64 + sp * 32 + (sg ^ scg) * 8,
             &As[buf][0][0][0] + sp * 8192 + (r0 + swi * 16) * 32);
    }
  };
  auto stageB = [&](int buf, int kt) {
#pragma unroll
    for (int c = 0; c < 2; c++) {
      int r0 = c * 64 + swi * 16;
      load16(Bblk + (size_t)(r0 + srow) * K + kt * 64 + sp * 32 + (sg ^ scg) * 8,
             &Bs[buf][0][0][0] + sp * 4096 + r0 * 32);
    }
  };

  stageA(0, 0, 0); stageA(0, 1, 0); stageB(0, 0);
  stageA(1, 0, 1);

#pragma unroll 1
  for (int i = 0; i < nit; i++) {
    const int ktA = 2 * i + 1;
    const int ktB = (2 * i + 2 < nkt) ? 2 * i + 2 : nkt - 1;
    const int ktC = (2 * i + 3 < nkt) ? 2 * i + 3 : nkt - 1;
    DRAIN2(); BARF();
    QLDA_(0); QLDB_(0, 0);
    stageA(1, 1, ktA); stageB(1, ktA);
    QMFMA_(0);
    BARF();
    QLDB_(0, 1);
    stageA(0, 0, ktB);
    QMFMA_(1);
    DRAIN2(); BARF();
    QLDA_(1); QLDB_(1, 0);
    stageA(0, 1, ktB); stageB(0, ktB);
    QMFMA_(0);
    BARF();
    QLDB_(1, 1);
    stageA(1, 0, ktC);
    QMFMA_(1);
  }
  asm volatile("s_waitcnt vmcnt(0)" ::: "memory");

#pragma unroll
  for (int mi = 0; mi < 4; mi++)
#pragma unroll
    for (int ni = 0; ni < 4; ni++)
#pragma unroll
      for (int r = 0; r < 4; r++) {
        int grow = m0 + wr4 * 64 + mi * 16 + l4 * 4 + r;
        int gcol = n0 + wc2 * 64 + ni * 16 + l15;
        Cb[(size_t)grow * N + gcol] = (bf16_t)acc[mi][ni][r];
      }
}

// ---------------- 256x256 4-phase GEMM (output projection; grid = 256 = 1 batch) ----------------
#define LDA_(BUF, MP) { \
  _Pragma("unroll") for (int mi = 0; mi < 4; mi++) { \
    _Pragma("unroll") for (int ks = 0; ks < 2; ks++) { \
      a[mi][ks] = *(const bf16x8_t*)&As[BUF][ks][wr * 128 + (MP) * 64 + mi * 16 + l15][(l4 ^ xr) * 8]; } } }

#define LDB_(BUF, NP) { \
  _Pragma("unroll") for (int n2 = 0; n2 < 2; n2++) { \
    _Pragma("unroll") for (int ks = 0; ks < 2; ks++) { \
      b[(NP) * 2 + n2][ks] = *(const bf16x8_t*)&Bs[BUF][ks][wc * 64 + (NP) * 32 + n2 * 16 + l15][(l4 ^ xr) * 8]; } } }

#define MFMA_Q(MP, NP) { \
  __builtin_amdgcn_s_setprio(1); \
  _Pragma("unroll") for (int mi = 0; mi < 4; mi++) { \
    _Pragma("unroll") for (int n2 = 0; n2 < 2; n2++) { \
      _Pragma("unroll") for (int ks = 0; ks < 2; ks++) { \
        acc[(MP) * 4 + mi][(NP) * 2 + n2] = __builtin_amdgcn_mfma_f32_16x16x32_bf16( \
            a[mi][ks], b[(NP) * 2 + n2][ks], acc[(MP) * 4 + mi][(NP) * 2 + n2], 0, 0, 0); } } } \
  __builtin_amdgcn_s_setprio(0); }

__global__ __launch_bounds__(512, 2) void gemm256_kernel(const bf16_t* __restrict__ A,
                                                         const bf16_t* __restrict__ Bm,
                                                         float* __restrict__ Cf,
                                                         int M, int N, int K) {
  __shared__ __align__(16) bf16_t As[2][2][256][32];  // 64 KiB
  __shared__ __align__(16) bf16_t Bs[2][2][256][32];  // 64 KiB
  const int t = threadIdx.x;
  const int lane = t & 63;
  const int w = t >> 6;
  const int wr = w >> 2;
  const int wc = w & 3;
  const int l15 = lane & 15, l4 = lane >> 4;
  const int xr = (l15 >> 1) & 3;
  const int sp = w >> 2;
  const int swi = w & 3;
  const int srow = lane >> 2;
  const int sg = lane & 3;
  const int scg = (srow >> 1) & 3;

  const int m0 = blockIdx.x * 256;
  const int n0 = blockIdx.y * 256;
  const bf16_t* Ablk = A + (size_t)m0 * K;
  const bf16_t* Bblk = Bm + (size_t)n0 * K;

  f32x4_t acc[8][4] = {};
  bf16x8_t a[4][2], b[4][2];

  const int nkt = K >> 6;
  const int nit = nkt >> 1;

  auto stageA = [&](int buf, int mp, int kt) {
#pragma unroll
    for (int c = 0; c < 2; c++) {
      int r0 = c * 128 + mp * 64;
      load16(Ablk + (size_t)(r0 + swi * 16 + srow) * K + kt * 64 + sp * 32 + (sg ^ scg) * 8,
             &As[buf][0][0][0] + sp * 8192 + (r0 + swi * 16) * 32);
    }
  };
  auto stageB = [&](int buf, int np, int kt) {
#pragma unroll
    for (int c = 0; c < 2; c++) {
      int r0 = (c * 2 + (swi >> 1)) * 64 + np * 32 + (swi & 1) * 16;
      load16(Bblk + (size_t)(r0 + srow) * K + kt * 64 + sp * 32 + (sg ^ scg) * 8,
             &Bs[buf][0][0][0] + sp * 8192 + r0 * 32);
    }
  };

  stageA(0, 0, 0); stageB(0, 0, 0); stageA(0, 1, 0); stageB(0, 1, 0);
  stageA(1, 0, 1); stageB(1, 0, 1);

#pragma unroll 1
  for (int i = 0; i < nit; i++) {
    const int ktA = 2 * i + 1;
    const int ktB = (2 * i + 2 < nkt) ? 2 * i + 2 : nkt - 1;
    const int ktC = (2 * i + 3 < nkt) ? 2 * i + 3 : nkt - 1;
    DRAIN4(); BARF();
    LDA_(0, 0); LDB_(0, 0); LDB_(0, 1);
    stageA(1, 1, ktA); stageB(1, 1, ktA);
    MFMA_Q(0, 0); MFMA_Q(0, 1);
    BARF();
    LDA_(0, 1);
    stageB(0, 1, ktB); stageB(0, 0, ktB);
    MFMA_Q(1, 0); MFMA_Q(1, 1);
    DRAIN4(); BARF();
    LDA_(1, 0); LDB_(1, 0); LDB_(1, 1);
    stageA(0, 1, ktB); stageA(0, 0, ktB);
    MFMA_Q(0, 0); MFMA_Q(0, 1);
    BARF();
    LDA_(1, 1);
    stageA(1, 0, ktC); stageB(1, 0, ktC);
    MFMA_Q(1, 0); MFMA_Q(1, 1);
  }
  asm volatile("s_waitcnt vmcnt(0)" ::: "memory");

#pragma unroll
  for (int ar = 0; ar < 8; ar++)
#pragma unroll
    for (int ni = 0; ni < 4; ni++)
#pragma unroll
      for (int r = 0; r < 4; r++) {
        int grow = m0 + wr * 128 + (ar >> 2) * 64 + (ar & 3) * 16 + l4 * 4 + r;
        int gcol = n0 + wc * 64 + ni * 16 + l15;
        Cf[(size_t)grow * N + gcol] = acc[ar][ni][r];
      }
}

// ---------------- RoPE + swizzled head layout for q,k ----------------
// Qro per (b,h,sblock): [lc(16)][row(64)][8]; Q additionally scaled by D^-0.5*log2e
// so attention's softmax runs in the exp2 domain with no per-score scale mul.
__global__ __launch_bounds__(320) void rope_kernel(const bf16_t* __restrict__ qkv,
                                                   const float* __restrict__ cosp,
                                                   const float* __restrict__ sinp,
                                                   bf16_t* __restrict__ Qro,
                                                   bf16_t* __restrict__ Kro) {
  const int tk = blockIdx.x;      // 0..8191 token
  const int b = tk >> 12;
  const int s = tk & 4095;
  const int sblock = s >> 6, row = s & 63;
  const int idx = threadIdx.x;    // 0..319: 256 q-chunks + 64 k-chunks
  int head, lc;
  const bf16_t* base;
  bf16_t* outp;
  float qs;
  if (idx < 256) {
    head = idx >> 4; lc = idx & 15;
    base = qkv + (size_t)tk * 3072 + head * 128;
    outp = Qro + ((size_t)(b * NH_ + head) * 64 + sblock) * 8192;
    qs = QSCALE_;
  } else {
    int i2 = idx - 256;
    head = i2 >> 4; lc = i2 & 15;
    base = qkv + (size_t)tk * 3072 + 2048 + head * 128;
    outp = Kro + ((size_t)(b * NKV_ + head) * 64 + sblock) * 8192;
    qs = 1.0f;
  }
  const int d0 = lc * 8;
  bf16x8_t x = *(const bf16x8_t*)(base + d0);
  const int d0p = (d0 < 64) ? d0 + 64 : d0 - 64;
  bf16x8_t xp = *(const bf16x8_t*)(base + d0p);
  const float sgn = (d0 < 64) ? -1.0f : 1.0f;
  const float* cb = cosp + (size_t)tk * 128 + d0;
  const float* sb = sinp + (size_t)tk * 128 + d0;
  bf16x8_t o;
#pragma unroll
  for (int e = 0; e < 8; e++)
    o[e] = (bf16_t)(((float)x[e] * cb[e] + sgn * (float)xp[e] * sb[e]) * qs);
  *(bf16x8_t*)(outp + (lc * 64 + row) * 8) = o;
}

// ---------------- V transpose into swizzled layout ----------------
// Vt per (b,kh,sblock): [sc(8)][d(128)][8]  where chunk content e runs along s
__global__ __launch_bounds__(256) void vtrans_kernel(const u16* __restrict__ qkv,
                                                     u16* __restrict__ vt) {
  __shared__ u16 tile[64][136];   // [s][d], d padded 128->136
  const int sblock = blockIdx.x;
  const int kh = blockIdx.y;
  const int b = blockIdx.z;
  const int t = threadIdx.x;
#pragma unroll
  for (int i = 0; i < 4; i++) {
    int f = t + 256 * i;
    int sl = f >> 4, c = f & 15;
    uint4 vv = *(const uint4*)(qkv + (size_t)(b * S_ + sblock * 64 + sl) * 3072 + 2560 + kh * 128 + c * 8);
    *(uint4*)&tile[sl][c * 8] = vv;
  }
  __syncthreads();
  u16* out = vt + ((size_t)(b * NKV_ + kh) * 64 + sblock) * 8192;
#pragma unroll
  for (int i = 0; i < 4; i++) {
    int g = t + 256 * i;
    int sc = g >> 7, d = g & 127;
    u16 e0 = tile[sc * 8 + 0][d], e1 = tile[sc * 8 + 1][d];
    u16 e2 = tile[sc * 8 + 2][d], e3 = tile[sc * 8 + 3][d];
    u16 e4 = tile[sc * 8 + 4][d], e5 = tile[sc * 8 + 5][d];
    u16 e6 = tile[sc * 8 + 6][d], e7 = tile[sc * 8 + 7][d];
    uint4 ov;
    ov.x = (u32)e0 | ((u32)e1 << 16);
    ov.y = (u32)e2 | ((u32)e3 << 16);
    ov.z = (u32)e4 | ((u32)e5 << 16);
    ov.w = (u32)e6 | ((u32)e7 << 16);
    *(uint4*)(out + (size_t)g * 8) = ov;
  }
}

// ---------------- GQA-packed block-sparse flash attention ----------------
// ONE 512-thread WG per (qblock, kv-head, batch): 8 waves = 4 heads x 2 row-tiles.
// K/V staged ONCE per kv-head (was twice), double-buffered, 1 barrier/iter.
// 75,776 B LDS -> 2 blocks/CU = 16 waves/CU (4/SIMD, 2x prev occupancy);
// grid = 512 blocks = exactly 2/CU, zero tail. exp2-domain softmax (scale
// folded into Q), uniform diag branch, T13 defer-max (THR=8, shift-invariant).
__global__ __launch_bounds__(512, 4) void attn_kernel(const bf16_t* __restrict__ Qr,
                                                      const bf16_t* __restrict__ Kr,
                                                      const bf16_t* __restrict__ Vt,
                                                      bf16_t* __restrict__ Ao) {
  __shared__ bf16_t Ks[2][8192];         // 2 x 16 KB [lc16][row64][8]
  __shared__ bf16_t Vs[2][8192];         // 2 x 16 KB [sc8][d128][8]
  __shared__ bf16_t Ps[8 * 640];         // per-wave 16x40 half-P tile (stride 40: 2-way max)
  const int qid = blockIdx.x;
  const int kh = blockIdx.y;
  const int b = blockIdx.z;
  const int t = threadIdx.x;
  const int lane = t & 63;
  const int w = t >> 6;                  // 0..7
  const int l15 = lane & 15, l4 = lane >> 4;
  const int h = kh * 4 + (w >> 1);       // wave-uniform head (4 heads per WG)
  int row0[2];
  row0[0] = ((w * 2) & 3) * 16;
  row0[1] = ((w * 2 + 1) & 3) * 16;

  // kept-block list (uniform per WG): [g0..g3, loc0..loc7], causal + dedup(first kept)
  int list[12];
  int nkeep = 0;
#pragma unroll
  for (int j = 0; j < 12; j++) {
    int cj;
    if (j < 4) cj = j * 16;
    else { cj = qid - 11 + j; cj = cj < 0 ? 0 : cj; cj = cj > 63 ? 63 : cj; }
    bool keep = (cj <= qid);
#pragma unroll
    for (int i = 0; i < j; i++) {
      int ci;
      if (i < 4) ci = i * 16;
      else { ci = qid - 11 + i; ci = ci < 0 ? 0 : ci; ci = ci > 63 ? 63 : ci; }
      if (ci == cj) keep = false;
    }
    if (keep) list[nkeep++] = cj;
  }

  const bf16_t* Qg = Qr + ((size_t)(b * NH_ + h) * 64 + qid) * 8192;
  const bf16_t* Kg = Kr + ((size_t)(b * NKV_ + kh) * 64) * 8192;
  const bf16_t* Vg = Vt + ((size_t)(b * NKV_ + kh) * 64) * 8192;

  // Q fragments straight from global (coalesced 256B runs), persistent
  bf16x8_t qa[2][4];
#pragma unroll
  for (int mt = 0; mt < 2; mt++)
#pragma unroll
    for (int ks = 0; ks < 4; ks++)
      qa[mt][ks] = *(const bf16x8_t*)(Qg + ((ks * 4 + l4) * 64 + row0[mt] + l15) * 8);

  bf16x8_t ones;
#pragma unroll
  for (int e = 0; e < 8; e++) ones[e] = (bf16_t)1.0f;

  float mi_r[2][4], li_r[2][4];
  f32x4_t oacc[2][8] = {};
#pragma unroll
  for (int mt = 0; mt < 2; mt++)
#pragma unroll
    for (int r = 0; r < 4; r++) { mi_r[mt][r] = -__builtin_inff(); li_r[mt][r] = 0.0f; }

  // prologue: stage first block into buffer 0 (512 threads -> 2 rounds each for K,V)
  {
    int cj = list[0];
#pragma unroll
    for (int i = 0; i < 2; i++) {
      int f = t + 512 * i;
      load16(Kg + (size_t)cj * 8192 + (size_t)f * 8, Ks[0] + (w * 64 + i * 512) * 8);
      load16(Vg + (size_t)cj * 8192 + (size_t)f * 8, Vs[0] + (w * 64 + i * 512) * 8);
    }
  }

  int cur = 0;
#pragma unroll 1
  for (int idx = 0; idx < nkeep; idx++) {
    const int cj = list[idx];
    __syncthreads();  // drains: buf[cur] loads complete; prev iter's LDS reads done
    if (idx + 1 < nkeep) {
      int cn = list[idx + 1];
#pragma unroll
      for (int i = 0; i < 2; i++) {
        int f = t + 512 * i;
        load16(Kg + (size_t)cn * 8192 + (size_t)f * 8, Ks[cur ^ 1] + (w * 64 + i * 512) * 8);
        load16(Vg + (size_t)cn * 8192 + (size_t)f * 8, Vs[cur ^ 1] + (w * 64 + i * 512) * 8);
      }
    }
    const bf16_t* ks_ = Ks[cur];
    const bf16_t* vs_ = Vs[cur];

    // S = Q K^T (exp2-domain, scale pre-folded into Q)
    f32x4_t sacc[2][4] = {};
#pragma unroll
    for (int ks = 0; ks < 4; ks++)
#pragma unroll
      for (int ni = 0; ni < 4; ni++) {
        bf16x8_t kb = *(const bf16x8_t*)&ks_[((ks * 4 + l4) * 64 + ni * 16 + l15) * 8];
#pragma unroll
        for (int mt = 0; mt < 2; mt++)
          sacc[mt][ni] = __builtin_amdgcn_mfma_f32_16x16x32_bf16(qa[mt][ks], kb, sacc[mt][ni], 0, 0, 0);
      }

    const bool diag = (cj == qid);
#pragma unroll
    for (int mt = 0; mt < 2; mt++) {
      if (diag) {  // wave-uniform branch: mask cost only on the 1 diagonal block
#pragma unroll
        for (int ni = 0; ni < 4; ni++)
#pragma unroll
          for (int r = 0; r < 4; r++)
            if ((ni * 16 + l15) > (row0[mt] + l4 * 4 + r)) sacc[mt][ni][r] += NEG2_;
      }
      float rmax[4];
#pragma unroll
      for (int r = 0; r < 4; r++)
        rmax[r] = fmaxf(fmaxf(sacc[mt][0][r], sacc[mt][1][r]),
                        fmaxf(sacc[mt][2][r], sacc[mt][3][r]));
#pragma unroll
      for (int msk = 1; msk < 16; msk <<= 1)
#pragma unroll
        for (int r = 0; r < 4; r++)
          rmax[r] = fmaxf(rmax[r], __shfl_xor(rmax[r], msk, 64));
      // T13 defer-max: softmax is shift-invariant; skip rescale unless growth > 8
      // (P then bounded by 2^8, exact math otherwise)
      bool need = false;
#pragma unroll
      for (int r = 0; r < 4; r++) need = need || (rmax[r] > mi_r[mt][r] + 8.0f);
      if (__any(need)) {
        float alpha[4];
#pragma unroll
        for (int r = 0; r < 4; r++) {
          float nm = fmaxf(mi_r[mt][r], rmax[r]);
          alpha[r] = exp2f(mi_r[mt][r] - nm);
          mi_r[mt][r] = nm;
        }
#pragma unroll
        for (int n2 = 0; n2 < 8; n2++)
#pragma unroll
          for (int r = 0; r < 4; r++)
            oacc[mt][n2][r] *= alpha[r];
#pragma unroll
        for (int r = 0; r < 4; r++) li_r[mt][r] *= alpha[r];
      }
      float p[4][4];
#pragma unroll
      for (int ni = 0; ni < 4; ni++)
#pragma unroll
        for (int r = 0; r < 4; r++)
          p[ni][r] = exp2f(sacc[mt][ni][r] - mi_r[mt][r]);

      // PV per 32-col half: store half-P -> read A-frag -> MFMA (per-wave region,
      // wave-internal LDS ordering; stride 40 => 2-way banks, free)
      bf16_t* psw = &Ps[w * 640];
      f32x4_t lacc = {};
#pragma unroll
      for (int kst = 0; kst < 2; kst++) {
#pragma unroll
        for (int n2i = 0; n2i < 2; n2i++)
#pragma unroll
          for (int r = 0; r < 4; r++)
            psw[(l4 * 4 + r) * 40 + n2i * 16 + l15] = (bf16_t)p[kst * 2 + n2i][r];
        bf16x8_t pa = *(const bf16x8_t*)&psw[l15 * 40 + l4 * 8];
        lacc = __builtin_amdgcn_mfma_f32_16x16x32_bf16(pa, ones, lacc, 0, 0, 0);
#pragma unroll
        for (int n2 = 0; n2 < 8; n2++) {
          bf16x8_t vb = *(const bf16x8_t*)&vs_[((kst * 4 + l4) * 128 + n2 * 16 + l15) * 8];
          oacc[mt][n2] = __builtin_amdgcn_mfma_f32_16x16x32_bf16(pa, vb, oacc[mt][n2], 0, 0, 0);
        }
      }
#pragma unroll
      for (int r = 0; r < 4; r++)
        li_r[mt][r] += lacc[r];
    }

    cur ^= 1;
  }

#pragma unroll
  for (int mt = 0; mt < 2; mt++) {
    float invl[4];
#pragma unroll
    for (int r = 0; r < 4; r++) invl[r] = 1.0f / li_r[mt][r];
#pragma unroll
    for (int n2 = 0; n2 < 8; n2++)
#pragma unroll
      for (int r = 0; r < 4; r++) {
        int m = row0[mt] + l4 * 4 + r;   // row within this head's 64-token block
        size_t idx = ((size_t)(b * S_ + qid * 64 + m)) * (NH_ * D_) + h * D_ + n2 * 16 + l15;
        Ao[idx] = (bf16_t)(oacc[mt][n2][r] * invl[r]);
      }
  }
}

// ---------------- launch ----------------
extern "C" void kernel_launch(void* const* d_in, const int* in_sizes, int n_in,
                              void* d_out, int out_size, void* d_ws, size_t ws_size,
                              hipStream_t stream) {
  const float* hs = (const float*)d_in[0];
  const float* cosp = (const float*)d_in[1];
  const float* sinp = (const float*)d_in[2];
  const float* Wq = (const float*)d_in[3];
  const float* Wk = (const float*)d_in[4];
  const float* Wv = (const float*)d_in[5];
  const float* Wo = (const float*)d_in[6];
  float* outp = (float*)d_out;

  char* ws = (char*)d_ws;
  bf16_t* Xb   = (bf16_t*)(ws);                 // 33,554,432 B (8192x2048)
  bf16_t* Wb   = (bf16_t*)(ws + 33554432);      // 12,582,912 B (3072x2048)
  bf16_t* Wob  = (bf16_t*)(ws + 46137344);      //  8,388,608 B (2048x2048)
  bf16_t* QKVo = (bf16_t*)(ws + 54525952);      // 50,331,648 B (8192x3072)
  bf16_t* Qr   = (bf16_t*)(ws + 104857600);     // 33,554,432 B (swizzled, pre-scaled)
  bf16_t* Kr   = (bf16_t*)(ws + 138412032);     //  8,388,608 B (swizzled)
  bf16_t* Vt   = (bf16_t*)(ws + 146800640);     //  8,388,608 B (swizzled)
  bf16_t* Ao   = QKVo;                          // alias: QKVo fully consumed before attn

  // fused fp32 -> bf16 converts (one launch)
  cvt_all_kernel<<<dim3(26624), dim3(256), 0, stream>>>(hs, Wq, Wk, Wv, Wo, Xb, Wb, Wob);

  // QKV projection: (8192x2048) @ (3072x2048)^T -> bf16  (256x128 tiles, 768 blocks)
  gemm_qkv_kernel<<<dim3(32, 24), dim3(512), 0, stream>>>(Xb, Wb, QKVo, 8192, 3072, 2048);
  // RoPE + swizzled head layouts (Q pre-scaled by D^-0.5*log2e)
  rope_kernel<<<dim3(8192), dim3(320), 0, stream>>>(QKVo, cosp, sinp, Qr, Kr);
  vtrans_kernel<<<dim3(64, NKV_, B_), dim3(256), 0, stream>>>((const u16*)QKVo, (u16*)Vt);
  // GQA-packed block-sparse attention: 512 blocks x 512 threads (4 heads/WG, K/V shared)
  attn_kernel<<<dim3(64, NKV_, B_), dim3(512), 0, stream>>>(Qr, Kr, Vt, Ao);
  // output projection: (8192x2048) @ (2048x2048)^T -> fp32 d_out (256 blocks = 1 batch)
  gemm256_kernel<<<dim3(32, 8), dim3(512), 0, stream>>>(Ao, Wob, outp, 8192, 2048, 2048);
}

// Round 6
// 476.616 us; speedup vs baseline: 1.4873x; 1.4873x over previous
//
#include <hip/hip_runtime.h>

typedef __bf16 bf16_t;
typedef __bf16 bf16x8_t __attribute__((ext_vector_type(8)));
typedef __bf16 bf16x4_t __attribute__((ext_vector_type(4)));
typedef float f32x4_t __attribute__((ext_vector_type(4)));
typedef unsigned short u16;
typedef unsigned int u32;

#define B_ 2
#define S_ 4096
#define NH_ 16
#define NKV_ 4
#define D_ 128
// attention runs in the exp2 domain: scale*log2e folded into Q at rope time
#define QSCALE_ 0.12751743f          // D^-0.5 * log2(e)
#define NEG2_ (-1442695040.0f)       // -1e9 * log2(e)

// async global->LDS, 16B per lane; LDS dest must be wave-uniform base (+lane*16 implicit)
__device__ __forceinline__ void load16(const bf16_t* g, bf16_t* l) {
  __builtin_amdgcn_global_load_lds(
      (__attribute__((address_space(1))) void*)(g),
      (__attribute__((address_space(3))) void*)(l),
      16, 0, 0);
}

// ---------------- fused fp32 -> bf16 convert (all 5 tensors, one launch) ----------------
__global__ __launch_bounds__(256) void cvt_all_kernel(const float* __restrict__ hs,
                                                      const float* __restrict__ Wq,
                                                      const float* __restrict__ Wk,
                                                      const float* __restrict__ Wv,
                                                      const float* __restrict__ Wo,
                                                      bf16_t* __restrict__ Xb,
                                                      bf16_t* __restrict__ Wb,
                                                      bf16_t* __restrict__ Wob) {
  int i = blockIdx.x * 256 + threadIdx.x;  // float4 index; ranges are 256-aligned (uniform branch)
  const float* src; bf16_t* dst; int local;
  if (i < 4194304)      { src = hs; dst = Xb;            local = i; }
  else if (i < 5242880) { src = Wq; dst = Wb;            local = i - 4194304; }
  else if (i < 5505024) { src = Wk; dst = Wb + 4194304;  local = i - 5242880; }
  else if (i < 5767168) { src = Wv; dst = Wb + 5242880;  local = i - 5505024; }
  else                  { src = Wo; dst = Wob;           local = i - 5767168; }
  float4 v = ((const float4*)src)[local];
  bf16x4_t o;
  o.x = (bf16_t)v.x; o.y = (bf16_t)v.y; o.z = (bf16_t)v.z; o.w = (bf16_t)v.w;
  *(bf16x4_t*)(dst + (size_t)local * 4) = o;
}

#define DRAIN2() asm volatile("s_waitcnt vmcnt(2)" ::: "memory")
#define DRAIN4() asm volatile("s_waitcnt vmcnt(4)" ::: "memory")
#define BARF() { __builtin_amdgcn_s_barrier(); asm volatile("" ::: "memory"); }

// ---------------- QKV GEMM: 256x128 tiles, 4-phase, 1 barrier/phase ----------------
#define QLDA_(BUF) { \
  _Pragma("unroll") for (int mi = 0; mi < 4; mi++) { \
    _Pragma("unroll") for (int ks = 0; ks < 2; ks++) { \
      a[mi][ks] = *(const bf16x8_t*)&As[BUF][ks][wr4 * 64 + mi * 16 + l15][(l4 ^ xr) * 8]; } } }

#define QLDB_(BUF, NP) { \
  _Pragma("unroll") for (int n2 = 0; n2 < 2; n2++) { \
    _Pragma("unroll") for (int ks = 0; ks < 2; ks++) { \
      b[(NP) * 2 + n2][ks] = *(const bf16x8_t*)&Bs[BUF][ks][wc2 * 64 + ((NP) * 2 + n2) * 16 + l15][(l4 ^ xr) * 8]; } } }

#define QMFMA_(NP) { \
  __builtin_amdgcn_s_setprio(1); \
  _Pragma("unroll") for (int mi = 0; mi < 4; mi++) { \
    _Pragma("unroll") for (int n2 = 0; n2 < 2; n2++) { \
      _Pragma("unroll") for (int ks = 0; ks < 2; ks++) { \
        acc[mi][(NP) * 2 + n2] = __builtin_amdgcn_mfma_f32_16x16x32_bf16( \
            a[mi][ks], b[(NP) * 2 + n2][ks], acc[mi][(NP) * 2 + n2], 0, 0, 0); } } } \
  __builtin_amdgcn_s_setprio(0); }

__global__ __launch_bounds__(512, 2) void gemm_qkv_kernel(const bf16_t* __restrict__ A,
                                                          const bf16_t* __restrict__ Bm,
                                                          bf16_t* __restrict__ Cb,
                                                          int M, int N, int K) {
  __shared__ __align__(16) bf16_t As[2][2][256][32];  // 64 KiB
  __shared__ __align__(16) bf16_t Bs[2][2][128][32];  // 32 KiB
  const int t = threadIdx.x;
  const int lane = t & 63;
  const int w = t >> 6;            // 0..7
  const int wr4 = w >> 1;          // 0..3 : M quarter (64 rows)
  const int wc2 = w & 1;           // 0..1 : N half (64 cols)
  const int l15 = lane & 15, l4 = lane >> 4;
  const int xr = (l15 >> 1) & 3;   // fragment-read granule XOR term
  const int sp = w >> 2;
  const int swi = w & 3;
  const int srow = lane >> 2;
  const int sg = lane & 3;
  const int scg = (srow >> 1) & 3;

  const int m0 = blockIdx.x * 256;
  const int n0 = blockIdx.y * 128;
  const bf16_t* Ablk = A + (size_t)m0 * K;
  const bf16_t* Bblk = Bm + (size_t)n0 * K;

  f32x4_t acc[4][4] = {};
  bf16x8_t a[4][2], b[4][2];

  const int nkt = K >> 6;
  const int nit = nkt >> 1;

  auto stageA = [&](int buf, int mp, int kt) {
#pragma unroll
    for (int c = 0; c < 2; c++) {
      int r0 = c * 128 + mp * 64;
      load16(Ablk + (size_t)(r0 + swi * 16 + srow) * K + kt * 64 + sp * 32 + (sg ^ scg) * 8,
             &As[buf][0][0][0] + sp * 8192 + (r0 + swi * 16) * 32);
    }
  };
  auto stageB = [&](int buf, int kt) {
#pragma unroll
    for (int c = 0; c < 2; c++) {
      int r0 = c * 64 + swi * 16;
      load16(Bblk + (size_t)(r0 + srow) * K + kt * 64 + sp * 32 + (sg ^ scg) * 8,
             &Bs[buf][0][0][0] + sp * 4096 + r0 * 32);
    }
  };

  stageA(0, 0, 0); stageA(0, 1, 0); stageB(0, 0);
  stageA(1, 0, 1);

#pragma unroll 1
  for (int i = 0; i < nit; i++) {
    const int ktA = 2 * i + 1;
    const int ktB = (2 * i + 2 < nkt) ? 2 * i + 2 : nkt - 1;
    const int ktC = (2 * i + 3 < nkt) ? 2 * i + 3 : nkt - 1;
    DRAIN2(); BARF();
    QLDA_(0); QLDB_(0, 0);
    stageA(1, 1, ktA); stageB(1, ktA);
    QMFMA_(0);
    BARF();
    QLDB_(0, 1);
    stageA(0, 0, ktB);
    QMFMA_(1);
    DRAIN2(); BARF();
    QLDA_(1); QLDB_(1, 0);
    stageA(0, 1, ktB); stageB(0, ktB);
    QMFMA_(0);
    BARF();
    QLDB_(1, 1);
    stageA(1, 0, ktC);
    QMFMA_(1);
  }
  asm volatile("s_waitcnt vmcnt(0)" ::: "memory");

#pragma unroll
  for (int mi = 0; mi < 4; mi++)
#pragma unroll
    for (int ni = 0; ni < 4; ni++)
#pragma unroll
      for (int r = 0; r < 4; r++) {
        int grow = m0 + wr4 * 64 + mi * 16 + l4 * 4 + r;
        int gcol = n0 + wc2 * 64 + ni * 16 + l15;
        Cb[(size_t)grow * N + gcol] = (bf16_t)acc[mi][ni][r];
      }
}

// ---------------- 256x256 4-phase GEMM (output projection; grid = 256 = 1 batch) ----------------
#define LDA_(BUF, MP) { \
  _Pragma("unroll") for (int mi = 0; mi < 4; mi++) { \
    _Pragma("unroll") for (int ks = 0; ks < 2; ks++) { \
      a[mi][ks] = *(const bf16x8_t*)&As[BUF][ks][wr * 128 + (MP) * 64 + mi * 16 + l15][(l4 ^ xr) * 8]; } } }

#define LDB_(BUF, NP) { \
  _Pragma("unroll") for (int n2 = 0; n2 < 2; n2++) { \
    _Pragma("unroll") for (int ks = 0; ks < 2; ks++) { \
      b[(NP) * 2 + n2][ks] = *(const bf16x8_t*)&Bs[BUF][ks][wc * 64 + (NP) * 32 + n2 * 16 + l15][(l4 ^ xr) * 8]; } } }

#define MFMA_Q(MP, NP) { \
  __builtin_amdgcn_s_setprio(1); \
  _Pragma("unroll") for (int mi = 0; mi < 4; mi++) { \
    _Pragma("unroll") for (int n2 = 0; n2 < 2; n2++) { \
      _Pragma("unroll") for (int ks = 0; ks < 2; ks++) { \
        acc[(MP) * 4 + mi][(NP) * 2 + n2] = __builtin_amdgcn_mfma_f32_16x16x32_bf16( \
            a[mi][ks], b[(NP) * 2 + n2][ks], acc[(MP) * 4 + mi][(NP) * 2 + n2], 0, 0, 0); } } } \
  __builtin_amdgcn_s_setprio(0); }

__global__ __launch_bounds__(512, 2) void gemm256_kernel(const bf16_t* __restrict__ A,
                                                         const bf16_t* __restrict__ Bm,
                                                         float* __restrict__ Cf,
                                                         int M, int N, int K) {
  __shared__ __align__(16) bf16_t As[2][2][256][32];  // 64 KiB
  __shared__ __align__(16) bf16_t Bs[2][2][256][32];  // 64 KiB
  const int t = threadIdx.x;
  const int lane = t & 63;
  const int w = t >> 6;
  const int wr = w >> 2;
  const int wc = w & 3;
  const int l15 = lane & 15, l4 = lane >> 4;
  const int xr = (l15 >> 1) & 3;
  const int sp = w >> 2;
  const int swi = w & 3;
  const int srow = lane >> 2;
  const int sg = lane & 3;
  const int scg = (srow >> 1) & 3;

  const int m0 = blockIdx.x * 256;
  const int n0 = blockIdx.y * 256;
  const bf16_t* Ablk = A + (size_t)m0 * K;
  const bf16_t* Bblk = Bm + (size_t)n0 * K;

  f32x4_t acc[8][4] = {};
  bf16x8_t a[4][2], b[4][2];

  const int nkt = K >> 6;
  const int nit = nkt >> 1;

  auto stageA = [&](int buf, int mp, int kt) {
#pragma unroll
    for (int c = 0; c < 2; c++) {
      int r0 = c * 128 + mp * 64;
      load16(Ablk + (size_t)(r0 + swi * 16 + srow) * K + kt * 64 + sp * 32 + (sg ^ scg) * 8,
             &As[buf][0][0][0] + sp * 8192 + (r0 + swi * 16) * 32);
    }
  };
  auto stageB = [&](int buf, int np, int kt) {
#pragma unroll
    for (int c = 0; c < 2; c++) {
      int r0 = (c * 2 + (swi >> 1)) * 64 + np * 32 + (swi & 1) * 16;
      load16(Bblk + (size_t)(r0 + srow) * K + kt * 64 + sp * 32 + (sg ^ scg) * 8,
             &Bs[buf][0][0][0] + sp * 8192 + r0 * 32);
    }
  };

  stageA(0, 0, 0); stageB(0, 0, 0); stageA(0, 1, 0); stageB(0, 1, 0);
  stageA(1, 0, 1); stageB(1, 0, 1);

#pragma unroll 1
  for (int i = 0; i < nit; i++) {
    const int ktA = 2 * i + 1;
    const int ktB = (2 * i + 2 < nkt) ? 2 * i + 2 : nkt - 1;
    const int ktC = (2 * i + 3 < nkt) ? 2 * i + 3 : nkt - 1;
    DRAIN4(); BARF();
    LDA_(0, 0); LDB_(0, 0); LDB_(0, 1);
    stageA(1, 1, ktA); stageB(1, 1, ktA);
    MFMA_Q(0, 0); MFMA_Q(0, 1);
    BARF();
    LDA_(0, 1);
    stageB(0, 1, ktB); stageB(0, 0, ktB);
    MFMA_Q(1, 0); MFMA_Q(1, 1);
    DRAIN4(); BARF();
    LDA_(1, 0); LDB_(1, 0); LDB_(1, 1);
    stageA(0, 1, ktB); stageA(0, 0, ktB);
    MFMA_Q(0, 0); MFMA_Q(0, 1);
    BARF();
    LDA_(1, 1);
    stageA(1, 0, ktC); stageB(1, 0, ktC);
    MFMA_Q(1, 0); MFMA_Q(1, 1);
  }
  asm volatile("s_waitcnt vmcnt(0)" ::: "memory");

#pragma unroll
  for (int ar = 0; ar < 8; ar++)
#pragma unroll
    for (int ni = 0; ni < 4; ni++)
#pragma unroll
      for (int r = 0; r < 4; r++) {
        int grow = m0 + wr * 128 + (ar >> 2) * 64 + (ar & 3) * 16 + l4 * 4 + r;
        int gcol = n0 + wc * 64 + ni * 16 + l15;
        Cf[(size_t)grow * N + gcol] = acc[ar][ni][r];
      }
}

// ---------------- RoPE + swizzled head layout for q,k ----------------
// Qro per (b,h,sblock): [lc(16)][row(64)][8]; Q additionally scaled by D^-0.5*log2e
// so attention's softmax runs in the exp2 domain with no per-score scale mul.
__global__ __launch_bounds__(320) void rope_kernel(const bf16_t* __restrict__ qkv,
                                                   const float* __restrict__ cosp,
                                                   const float* __restrict__ sinp,
                                                   bf16_t* __restrict__ Qro,
                                                   bf16_t* __restrict__ Kro) {
  const int tk = blockIdx.x;      // 0..8191 token
  const int b = tk >> 12;
  const int s = tk & 4095;
  const int sblock = s >> 6, row = s & 63;
  const int idx = threadIdx.x;    // 0..319: 256 q-chunks + 64 k-chunks
  int head, lc;
  const bf16_t* base;
  bf16_t* outp;
  float qs;
  if (idx < 256) {
    head = idx >> 4; lc = idx & 15;
    base = qkv + (size_t)tk * 3072 + head * 128;
    outp = Qro + ((size_t)(b * NH_ + head) * 64 + sblock) * 8192;
    qs = QSCALE_;
  } else {
    int i2 = idx - 256;
    head = i2 >> 4; lc = i2 & 15;
    base = qkv + (size_t)tk * 3072 + 2048 + head * 128;
    outp = Kro + ((size_t)(b * NKV_ + head) * 64 + sblock) * 8192;
    qs = 1.0f;
  }
  const int d0 = lc * 8;
  bf16x8_t x = *(const bf16x8_t*)(base + d0);
  const int d0p = (d0 < 64) ? d0 + 64 : d0 - 64;
  bf16x8_t xp = *(const bf16x8_t*)(base + d0p);
  const float sgn = (d0 < 64) ? -1.0f : 1.0f;
  const float* cb = cosp + (size_t)tk * 128 + d0;
  const float* sb = sinp + (size_t)tk * 128 + d0;
  bf16x8_t o;
#pragma unroll
  for (int e = 0; e < 8; e++)
    o[e] = (bf16_t)(((float)x[e] * cb[e] + sgn * (float)xp[e] * sb[e]) * qs);
  *(bf16x8_t*)(outp + (lc * 64 + row) * 8) = o;
}

// ---------------- V transpose into swizzled layout ----------------
// Vt per (b,kh,sblock): [sc(8)][d(128)][8]  where chunk content e runs along s
__global__ __launch_bounds__(256) void vtrans_kernel(const u16* __restrict__ qkv,
                                                     u16* __restrict__ vt) {
  __shared__ u16 tile[64][136];   // [s][d], d padded 128->136
  const int sblock = blockIdx.x;
  const int kh = blockIdx.y;
  const int b = blockIdx.z;
  const int t = threadIdx.x;
#pragma unroll
  for (int i = 0; i < 4; i++) {
    int f = t + 256 * i;
    int sl = f >> 4, c = f & 15;
    uint4 vv = *(const uint4*)(qkv + (size_t)(b * S_ + sblock * 64 + sl) * 3072 + 2560 + kh * 128 + c * 8);
    *(uint4*)&tile[sl][c * 8] = vv;
  }
  __syncthreads();
  u16* out = vt + ((size_t)(b * NKV_ + kh) * 64 + sblock) * 8192;
#pragma unroll
  for (int i = 0; i < 4; i++) {
    int g = t + 256 * i;
    int sc = g >> 7, d = g & 127;
    u16 e0 = tile[sc * 8 + 0][d], e1 = tile[sc * 8 + 1][d];
    u16 e2 = tile[sc * 8 + 2][d], e3 = tile[sc * 8 + 3][d];
    u16 e4 = tile[sc * 8 + 4][d], e5 = tile[sc * 8 + 5][d];
    u16 e6 = tile[sc * 8 + 6][d], e7 = tile[sc * 8 + 7][d];
    uint4 ov;
    ov.x = (u32)e0 | ((u32)e1 << 16);
    ov.y = (u32)e2 | ((u32)e3 << 16);
    ov.z = (u32)e4 | ((u32)e5 << 16);
    ov.w = (u32)e6 | ((u32)e7 << 16);
    *(uint4*)(out + (size_t)g * 8) = ov;
  }
}

// ---------------- GQA-packed block-sparse flash attention ----------------
// ONE 512-thread WG per (qblock, kv-head, batch): 8 waves = 4 heads x 2 row-tiles.
// K/V staged ONCE per kv-head, double-buffered, 1 barrier/iter.
// launch_bounds(512, 2): round-5's (512,4) capped VGPR at 128 < ~150 live state
// -> allocator collapsed to 64 VGPR + 1.3 GB scratch spill (730 MB WRITE_SIZE).
// With cap 256 the allocator lands ~124 (round-4 evidence); if <=128 the HW
// gives 2 blocks/CU (LDS 75.8K x2 fits 160K), else 1 block/CU — never spills.
__global__ __launch_bounds__(512, 2) void attn_kernel(const bf16_t* __restrict__ Qr,
                                                      const bf16_t* __restrict__ Kr,
                                                      const bf16_t* __restrict__ Vt,
                                                      bf16_t* __restrict__ Ao) {
  __shared__ bf16_t Ks[2][8192];         // 2 x 16 KB [lc16][row64][8]
  __shared__ bf16_t Vs[2][8192];         // 2 x 16 KB [sc8][d128][8]
  __shared__ bf16_t Ps[8 * 640];         // per-wave 16x40 half-P tile (stride 40: 2-way max)
  const int qid = blockIdx.x;
  const int kh = blockIdx.y;
  const int b = blockIdx.z;
  const int t = threadIdx.x;
  const int lane = t & 63;
  const int w = t >> 6;                  // 0..7
  const int l15 = lane & 15, l4 = lane >> 4;
  const int h = kh * 4 + (w >> 1);       // wave-uniform head (4 heads per WG)
  int row0[2];
  row0[0] = ((w * 2) & 3) * 16;
  row0[1] = ((w * 2 + 1) & 3) * 16;

  // kept-block list (uniform per WG): [g0..g3, loc0..loc7], causal + dedup(first kept)
  int list[12];
  int nkeep = 0;
#pragma unroll
  for (int j = 0; j < 12; j++) {
    int cj;
    if (j < 4) cj = j * 16;
    else { cj = qid - 11 + j; cj = cj < 0 ? 0 : cj; cj = cj > 63 ? 63 : cj; }
    bool keep = (cj <= qid);
#pragma unroll
    for (int i = 0; i < j; i++) {
      int ci;
      if (i < 4) ci = i * 16;
      else { ci = qid - 11 + i; ci = ci < 0 ? 0 : ci; ci = ci > 63 ? 63 : ci; }
      if (ci == cj) keep = false;
    }
    if (keep) list[nkeep++] = cj;
  }

  const bf16_t* Qg = Qr + ((size_t)(b * NH_ + h) * 64 + qid) * 8192;
  const bf16_t* Kg = Kr + ((size_t)(b * NKV_ + kh) * 64) * 8192;
  const bf16_t* Vg = Vt + ((size_t)(b * NKV_ + kh) * 64) * 8192;

  // Q fragments straight from global (coalesced 256B runs), persistent
  bf16x8_t qa[2][4];
#pragma unroll
  for (int mt = 0; mt < 2; mt++)
#pragma unroll
    for (int ks = 0; ks < 4; ks++)
      qa[mt][ks] = *(const bf16x8_t*)(Qg + ((ks * 4 + l4) * 64 + row0[mt] + l15) * 8);

  bf16x8_t ones;
#pragma unroll
  for (int e = 0; e < 8; e++) ones[e] = (bf16_t)1.0f;

  float mi_r[2][4], li_r[2][4];
  f32x4_t oacc[2][8] = {};
#pragma unroll
  for (int mt = 0; mt < 2; mt++)
#pragma unroll
    for (int r = 0; r < 4; r++) { mi_r[mt][r] = -__builtin_inff(); li_r[mt][r] = 0.0f; }

  // prologue: stage first block into buffer 0 (512 threads -> 2 rounds each for K,V)
  {
    int cj = list[0];
#pragma unroll
    for (int i = 0; i < 2; i++) {
      int f = t + 512 * i;
      load16(Kg + (size_t)cj * 8192 + (size_t)f * 8, Ks[0] + (w * 64 + i * 512) * 8);
      load16(Vg + (size_t)cj * 8192 + (size_t)f * 8, Vs[0] + (w * 64 + i * 512) * 8);
    }
  }

  int cur = 0;
#pragma unroll 1
  for (int idx = 0; idx < nkeep; idx++) {
    const int cj = list[idx];
    __syncthreads();  // drains: buf[cur] loads complete; prev iter's LDS reads done
    if (idx + 1 < nkeep) {
      int cn = list[idx + 1];
#pragma unroll
      for (int i = 0; i < 2; i++) {
        int f = t + 512 * i;
        load16(Kg + (size_t)cn * 8192 + (size_t)f * 8, Ks[cur ^ 1] + (w * 64 + i * 512) * 8);
        load16(Vg + (size_t)cn * 8192 + (size_t)f * 8, Vs[cur ^ 1] + (w * 64 + i * 512) * 8);
      }
    }
    const bf16_t* ks_ = Ks[cur];
    const bf16_t* vs_ = Vs[cur];

    // S = Q K^T (exp2-domain, scale pre-folded into Q)
    f32x4_t sacc[2][4] = {};
#pragma unroll
    for (int ks = 0; ks < 4; ks++)
#pragma unroll
      for (int ni = 0; ni < 4; ni++) {
        bf16x8_t kb = *(const bf16x8_t*)&ks_[((ks * 4 + l4) * 64 + ni * 16 + l15) * 8];
#pragma unroll
        for (int mt = 0; mt < 2; mt++)
          sacc[mt][ni] = __builtin_amdgcn_mfma_f32_16x16x32_bf16(qa[mt][ks], kb, sacc[mt][ni], 0, 0, 0);
      }

    const bool diag = (cj == qid);
#pragma unroll
    for (int mt = 0; mt < 2; mt++) {
      if (diag) {  // wave-uniform branch: mask cost only on the 1 diagonal block
#pragma unroll
        for (int ni = 0; ni < 4; ni++)
#pragma unroll
          for (int r = 0; r < 4; r++)
            if ((ni * 16 + l15) > (row0[mt] + l4 * 4 + r)) sacc[mt][ni][r] += NEG2_;
      }
      float rmax[4];
#pragma unroll
      for (int r = 0; r < 4; r++)
        rmax[r] = fmaxf(fmaxf(sacc[mt][0][r], sacc[mt][1][r]),
                        fmaxf(sacc[mt][2][r], sacc[mt][3][r]));
#pragma unroll
      for (int msk = 1; msk < 16; msk <<= 1)
#pragma unroll
        for (int r = 0; r < 4; r++)
          rmax[r] = fmaxf(rmax[r], __shfl_xor(rmax[r], msk, 64));
      // T13 defer-max: softmax is shift-invariant; skip rescale unless growth > 8
      // (P then bounded by 2^8, exact math otherwise)
      bool need = false;
#pragma unroll
      for (int r = 0; r < 4; r++) need = need || (rmax[r] > mi_r[mt][r] + 8.0f);
      if (__any(need)) {
        float alpha[4];
#pragma unroll
        for (int r = 0; r < 4; r++) {
          float nm = fmaxf(mi_r[mt][r], rmax[r]);
          alpha[r] = exp2f(mi_r[mt][r] - nm);
          mi_r[mt][r] = nm;
        }
#pragma unroll
        for (int n2 = 0; n2 < 8; n2++)
#pragma unroll
          for (int r = 0; r < 4; r++)
            oacc[mt][n2][r] *= alpha[r];
#pragma unroll
        for (int r = 0; r < 4; r++) li_r[mt][r] *= alpha[r];
      }
      float p[4][4];
#pragma unroll
      for (int ni = 0; ni < 4; ni++)
#pragma unroll
        for (int r = 0; r < 4; r++)
          p[ni][r] = exp2f(sacc[mt][ni][r] - mi_r[mt][r]);

      // PV per 32-col half: store half-P -> read A-frag -> MFMA (per-wave region,
      // wave-internal LDS ordering; stride 40 => 2-way banks, free)
      bf16_t* psw = &Ps[w * 640];
      f32x4_t lacc = {};
#pragma unroll
      for (int kst = 0; kst < 2; kst++) {
#pragma unroll
        for (int n2i = 0; n2i < 2; n2i++)
#pragma unroll
          for (int r = 0; r < 4; r++)
            psw[(l4 * 4 + r) * 40 + n2i * 16 + l15] = (bf16_t)p[kst * 2 + n2i][r];
        bf16x8_t pa = *(const bf16x8_t*)&psw[l15 * 40 + l4 * 8];
        lacc = __builtin_amdgcn_mfma_f32_16x16x32_bf16(pa, ones, lacc, 0, 0, 0);
#pragma unroll
        for (int n2 = 0; n2 < 8; n2++) {
          bf16x8_t vb = *(const bf16x8_t*)&vs_[((kst * 4 + l4) * 128 + n2 * 16 + l15) * 8];
          oacc[mt][n2] = __builtin_amdgcn_mfma_f32_16x16x32_bf16(pa, vb, oacc[mt][n2], 0, 0, 0);
        }
      }
#pragma unroll
      for (int r = 0; r < 4; r++)
        li_r[mt][r] += lacc[r];
    }

    cur ^= 1;
  }

#pragma unroll
  for (int mt = 0; mt < 2; mt++) {
    float invl[4];
#pragma unroll
    for (int r = 0; r < 4; r++) invl[r] = 1.0f / li_r[mt][r];
#pragma unroll
    for (int n2 = 0; n2 < 8; n2++)
#pragma unroll
      for (int r = 0; r < 4; r++) {
        int m = row0[mt] + l4 * 4 + r;   // row within this head's 64-token block
        size_t idx = ((size_t)(b * S_ + qid * 64 + m)) * (NH_ * D_) + h * D_ + n2 * 16 + l15;
        Ao[idx] = (bf16_t)(oacc[mt][n2][r] * invl[r]);
      }
  }
}

// ---------------- launch ----------------
extern "C" void kernel_launch(void* const* d_in, const int* in_sizes, int n_in,
                              void* d_out, int out_size, void* d_ws, size_t ws_size,
                              hipStream_t stream) {
  const float* hs = (const float*)d_in[0];
  const float* cosp = (const float*)d_in[1];
  const float* sinp = (const float*)d_in[2];
  const float* Wq = (const float*)d_in[3];
  const float* Wk = (const float*)d_in[4];
  const float* Wv = (const float*)d_in[5];
  const float* Wo = (const float*)d_in[6];
  float* outp = (float*)d_out;

  char* ws = (char*)d_ws;
  bf16_t* Xb   = (bf16_t*)(ws);                 // 33,554,432 B (8192x2048)
  bf16_t* Wb   = (bf16_t*)(ws + 33554432);      // 12,582,912 B (3072x2048)
  bf16_t* Wob  = (bf16_t*)(ws + 46137344);      //  8,388,608 B (2048x2048)
  bf16_t* QKVo = (bf16_t*)(ws + 54525952);      // 50,331,648 B (8192x3072)
  bf16_t* Qr   = (bf16_t*)(ws + 104857600);     // 33,554,432 B (swizzled, pre-scaled)
  bf16_t* Kr   = (bf16_t*)(ws + 138412032);     //  8,388,608 B (swizzled)
  bf16_t* Vt   = (bf16_t*)(ws + 146800640);     //  8,388,608 B (swizzled)
  bf16_t* Ao   = QKVo;                          // alias: QKVo fully consumed before attn

  // fused fp32 -> bf16 converts (one launch)
  cvt_all_kernel<<<dim3(26624), dim3(256), 0, stream>>>(hs, Wq, Wk, Wv, Wo, Xb, Wb, Wob);

  // QKV projection: (8192x2048) @ (3072x2048)^T -> bf16  (256x128 tiles, 768 blocks)
  gemm_qkv_kernel<<<dim3(32, 24), dim3(512), 0, stream>>>(Xb, Wb, QKVo, 8192, 3072, 2048);
  // RoPE + swizzled head layouts (Q pre-scaled by D^-0.5*log2e)
  rope_kernel<<<dim3(8192), dim3(320), 0, stream>>>(QKVo, cosp, sinp, Qr, Kr);
  vtrans_kernel<<<dim3(64, NKV_, B_), dim3(256), 0, stream>>>((const u16*)QKVo, (u16*)Vt);
  // GQA-packed block-sparse attention: 512 blocks x 512 threads (4 heads/WG, K/V shared)
  attn_kernel<<<dim3(64, NKV_, B_), dim3(512), 0, stream>>>(Qr, Kr, Vt, Ao);
  // output projection: (8192x2048) @ (2048x2048)^T -> fp32 d_out (256 blocks = 1 batch)
  gemm256_kernel<<<dim3(32, 8), dim3(512), 0, stream>>>(Ao, Wob, outp, 8192, 2048, 2048);
}